// Round 10
// baseline (929.840 us; speedup 1.0000x reference)
//
#include <hip/hip_runtime.h>
#include <math.h>

#define N_NODES 50000
#define N_EDGES 1600000
#define DIM 64
#define HEADS 8
#define EDGE_DIM 32

#define NB 512      // destination buckets
#define NPB 98      // nodes per bucket (98*512 = 50176 >= 50000)
#define ACAP 4096   // per-bucket capacity (mean 3125, sd ~56 -> 17 sigma)
#define PART_T 256
#define EPT 4
#define PART_E (PART_T * EPT)  // 1024 edges per partition block

typedef __fp16 h2 __attribute__((ext_vector_type(2)));

// ---- bf16 helpers (RNE round via bit trick; inputs are finite) ----
__device__ __forceinline__ unsigned int f2bf(float f) {
    union { float f; unsigned int u; } c; c.f = f;
    unsigned int u = c.u;
    return (u + 0x7FFFu + ((u >> 16) & 1u)) >> 16;
}
__device__ __forceinline__ float bf_lo(unsigned int u) { return __uint_as_float(u << 16); }
__device__ __forceinline__ float bf_hi(unsigned int u) { return __uint_as_float(u & 0xFFFF0000u); }

// ---------------- K_prep: pack MLP weights as half2 pairs ----------------
__global__ __launch_bounds__(1024) void pack_weights(
    const float* __restrict__ We1, const float* __restrict__ We2,
    h2* __restrict__ w1p, h2* __restrict__ w2p)
{
    const int t = threadIdx.x;
    if (t < 512) {
        const int c = t >> 4, kk = t & 15;
        w1p[t] = __builtin_amdgcn_cvt_pkrtz(We1[(2 * kk) * EDGE_DIM + c],
                                            We1[(2 * kk + 1) * EDGE_DIM + c]);
    } else if (t < 512 + 128) {
        const int u = t - 512;
        const int h = u >> 4, cc = u & 15;
        w2p[u] = __builtin_amdgcn_cvt_pkrtz(We2[(2 * cc) * HEADS + h],
                                            We2[(2 * cc + 1) * HEADS + h]);
    }
}

// ---------------- K_A: MLP + bucket partition (high-occupancy) ----------------
// Streams ei + edge_attr, computes the edge MLP, writes {jl<<24|i, bias[8]bf16}
// into per-bucket regions via block-reserved sequential chunks.
__global__ __launch_bounds__(256) void mlp_partition(
    const int* __restrict__ ei,
    const float* __restrict__ edge_attr,
    const h2* __restrict__ w1p, const float* __restrict__ be1,
    const h2* __restrict__ w2p, const float* __restrict__ be2,
    int* __restrict__ gcur,
    unsigned int* __restrict__ A_rec, uint4* __restrict__ A_bias)
{
    __shared__ int cnt[NB];
    __shared__ int base[NB];
    const int tid = threadIdx.x;
    for (int t = tid; t < NB; t += PART_T) cnt[t] = 0;
    __syncthreads();
    const int e0 = blockIdx.x * PART_E;
    #pragma unroll
    for (int k = 0; k < EPT; ++k) {
        const int e = e0 + k * PART_T + tid;
        if (e < N_EDGES) atomicAdd(&cnt[ei[N_EDGES + e] / NPB], 1);
    }
    __syncthreads();
    for (int t = tid; t < NB; t += PART_T) {
        base[t] = (cnt[t] > 0) ? atomicAdd(&gcur[t], cnt[t]) : 0;
        cnt[t] = 0;  // reuse as local cursor
    }
    __syncthreads();
    for (int k = 0; k < EPT; ++k) {
        const int e = e0 + k * PART_T + tid;
        if (e >= N_EDGES) break;
        const int i = ei[e];
        const int j = ei[N_EDGES + e];
        const int b = j / NPB;
        const int jl = j - b * NPB;
        float a[EDGE_DIM];
        const float4* ar = (const float4*)(edge_attr + (size_t)e * EDGE_DIM);
        #pragma unroll
        for (int q = 0; q < EDGE_DIM / 4; ++q) {
            float4 v = ar[q];
            a[q * 4 + 0] = v.x; a[q * 4 + 1] = v.y;
            a[q * 4 + 2] = v.z; a[q * 4 + 3] = v.w;
        }
        h2 a2[EDGE_DIM / 2];
        #pragma unroll
        for (int kk = 0; kk < EDGE_DIM / 2; ++kk)
            a2[kk] = __builtin_amdgcn_cvt_pkrtz(a[2 * kk], a[2 * kk + 1]);
        float sil[EDGE_DIM];
        #pragma unroll 8
        for (int c = 0; c < EDGE_DIM; ++c) {
            float s = be1[c];
            #pragma unroll
            for (int kk = 0; kk < EDGE_DIM / 2; ++kk)
                s = __builtin_amdgcn_fdot2(a2[kk], w1p[c * 16 + kk], s, false);
            sil[c] = __fdividef(s, 1.0f + __expf(-s));
        }
        h2 s2[EDGE_DIM / 2];
        #pragma unroll
        for (int cc = 0; cc < EDGE_DIM / 2; ++cc)
            s2[cc] = __builtin_amdgcn_cvt_pkrtz(sil[2 * cc], sil[2 * cc + 1]);
        float b0f = be2[0], b1f = be2[1], b2f = be2[2], b3f = be2[3];
        float b4f = be2[4], b5f = be2[5], b6f = be2[6], b7f = be2[7];
        #pragma unroll
        for (int cc = 0; cc < EDGE_DIM / 2; ++cc) {
            b0f = __builtin_amdgcn_fdot2(s2[cc], w2p[0 * 16 + cc], b0f, false);
            b1f = __builtin_amdgcn_fdot2(s2[cc], w2p[1 * 16 + cc], b1f, false);
            b2f = __builtin_amdgcn_fdot2(s2[cc], w2p[2 * 16 + cc], b2f, false);
            b3f = __builtin_amdgcn_fdot2(s2[cc], w2p[3 * 16 + cc], b3f, false);
            b4f = __builtin_amdgcn_fdot2(s2[cc], w2p[4 * 16 + cc], b4f, false);
            b5f = __builtin_amdgcn_fdot2(s2[cc], w2p[5 * 16 + cc], b5f, false);
            b6f = __builtin_amdgcn_fdot2(s2[cc], w2p[6 * 16 + cc], b6f, false);
            b7f = __builtin_amdgcn_fdot2(s2[cc], w2p[7 * 16 + cc], b7f, false);
        }
        uint4 br;
        br.x = f2bf(b0f) | (f2bf(b1f) << 16);
        br.y = f2bf(b2f) | (f2bf(b3f) << 16);
        br.z = f2bf(b4f) | (f2bf(b5f) << 16);
        br.w = f2bf(b6f) | (f2bf(b7f) << 16);
        const int lp = base[b] + atomicAdd(&cnt[b], 1);
        if (lp < ACAP) {
            A_rec[(size_t)b * ACAP + lp]  = ((unsigned)jl << 24) | (unsigned)i;
            A_bias[(size_t)b * ACAP + lp] = br;
        }
    }
}

// ---------------- K1: Q/K/V projections; K,V packed bf16 into one uint row ----------------
__global__ __launch_bounds__(256) void qkv_proj(
    const float* __restrict__ x,
    const float* __restrict__ WQ, const float* __restrict__ bQ,
    const float* __restrict__ WK, const float* __restrict__ bK,
    const float* __restrict__ WV, const float* __restrict__ bV,
    float* __restrict__ Q, unsigned int* __restrict__ KV)
{
    __shared__ float sWQ[DIM * DIM];
    __shared__ float sWK[DIM * DIM];
    __shared__ float sWV[DIM * DIM];
    for (int t = threadIdx.x; t < DIM * DIM; t += blockDim.x) {
        sWQ[t] = WQ[t]; sWK[t] = WK[t]; sWV[t] = WV[t];
    }
    __syncthreads();
    const int lane = threadIdx.x & 63;
    const int wave = threadIdx.x >> 6;
    const int n = blockIdx.x * 4 + wave;
    if (n >= N_NODES) return;
    float xl = x[(size_t)n * DIM + lane];
    float aq = bQ[lane], ak = bK[lane], av = bV[lane];
    #pragma unroll
    for (int k = 0; k < DIM; ++k) {
        float xv = __shfl(xl, k, 64);
        aq += xv * sWQ[k * DIM + lane];
        ak += xv * sWK[k * DIM + lane];
        av += xv * sWV[k * DIM + lane];
    }
    Q[(size_t)n * DIM + lane] = aq;
    KV[(size_t)n * DIM + lane] = f2bf(ak) | (f2bf(av) << 16);  // K lo, V hi
}

// ---------------- K_B: per-bucket attention via LDS accumulation ----------------
// One block per bucket; records processed in arrival order (NO sort needed).
// num[node][dim] / den[node][head] accumulate in LDS via float atomics
// (lane=dim -> consecutive dwords -> 2-way bank aliasing = free).
// Q rows staged in LDS. ~53 KB LDS, 1024 thr -> 2 blocks/CU, full occupancy.
__global__ __launch_bounds__(1024) void bucket_attn2(
    const int* __restrict__ gcur,
    const unsigned int* __restrict__ A_rec,
    const uint4* __restrict__ A_bias,
    const float* __restrict__ Q, const unsigned int* __restrict__ KV,
    const float* __restrict__ WO, const float* __restrict__ bO,
    float* __restrict__ out)
{
    __shared__ float sQ[NPB * DIM];      // 25088 B
    __shared__ float sNum[NPB * DIM];    // 25088 B
    __shared__ float sDen[NPB * HEADS];  // 3136 B
    const int tid = threadIdx.x;
    const int b = blockIdx.x;
    const int jbase = b * NPB;
    const int nb = min(gcur[b], ACAP);
    for (int t = tid; t < NPB * DIM; t += 1024) {
        sNum[t] = 0.0f;
        const int j = jbase + (t >> 6);
        sQ[t] = (j < N_NODES) ? Q[(size_t)j * DIM + (t & 63)] : 0.0f;
    }
    for (int t = tid; t < NPB * HEADS; t += 1024) sDen[t] = 0.0f;
    __syncthreads();
    const int lane = tid & 63;
    const int wave = tid >> 6;  // 0..15
    const int h = lane >> 3;
    const unsigned short* bias16 = (const unsigned short*)A_bias;
    const size_t rbase = (size_t)b * ACAP;
    const float inv_sqrt_dk = 0.35355339059327373f;
    int r = wave;
    for (; r + 48 < nb; r += 64) {
        const unsigned int rec0 = A_rec[rbase + r +  0];
        const unsigned int rec1 = A_rec[rbase + r + 16];
        const unsigned int rec2 = A_rec[rbase + r + 32];
        const unsigned int rec3 = A_rec[rbase + r + 48];
        const unsigned int u0 = KV[(size_t)(rec0 & 0xFFFFFFu) * DIM + lane];
        const unsigned int u1 = KV[(size_t)(rec1 & 0xFFFFFFu) * DIM + lane];
        const unsigned int u2 = KV[(size_t)(rec2 & 0xFFFFFFu) * DIM + lane];
        const unsigned int u3 = KV[(size_t)(rec3 & 0xFFFFFFu) * DIM + lane];
        const float bb0 = bf_lo((unsigned int)bias16[(rbase + r +  0) * 8 + h]);
        const float bb1 = bf_lo((unsigned int)bias16[(rbase + r + 16) * 8 + h]);
        const float bb2 = bf_lo((unsigned int)bias16[(rbase + r + 32) * 8 + h]);
        const float bb3 = bf_lo((unsigned int)bias16[(rbase + r + 48) * 8 + h]);
        const int jl0 = rec0 >> 24, jl1 = rec1 >> 24, jl2 = rec2 >> 24, jl3 = rec3 >> 24;
        float d0 = sQ[jl0 * DIM + lane] * bf_lo(u0);
        float d1 = sQ[jl1 * DIM + lane] * bf_lo(u1);
        float d2 = sQ[jl2 * DIM + lane] * bf_lo(u2);
        float d3 = sQ[jl3 * DIM + lane] * bf_lo(u3);
        d0 += __shfl_xor(d0, 1, 64); d1 += __shfl_xor(d1, 1, 64);
        d2 += __shfl_xor(d2, 1, 64); d3 += __shfl_xor(d3, 1, 64);
        d0 += __shfl_xor(d0, 2, 64); d1 += __shfl_xor(d1, 2, 64);
        d2 += __shfl_xor(d2, 2, 64); d3 += __shfl_xor(d3, 2, 64);
        d0 += __shfl_xor(d0, 4, 64); d1 += __shfl_xor(d1, 4, 64);
        d2 += __shfl_xor(d2, 4, 64); d3 += __shfl_xor(d3, 4, 64);
        const float e0 = __expf(d0 * inv_sqrt_dk + bb0);
        const float e1 = __expf(d1 * inv_sqrt_dk + bb1);
        const float e2 = __expf(d2 * inv_sqrt_dk + bb2);
        const float e3 = __expf(d3 * inv_sqrt_dk + bb3);
        atomicAdd(&sNum[jl0 * DIM + lane], e0 * bf_hi(u0));
        atomicAdd(&sNum[jl1 * DIM + lane], e1 * bf_hi(u1));
        atomicAdd(&sNum[jl2 * DIM + lane], e2 * bf_hi(u2));
        atomicAdd(&sNum[jl3 * DIM + lane], e3 * bf_hi(u3));
        if ((lane & 7) == 0) {
            atomicAdd(&sDen[jl0 * HEADS + h], e0);
            atomicAdd(&sDen[jl1 * HEADS + h], e1);
            atomicAdd(&sDen[jl2 * HEADS + h], e2);
            atomicAdd(&sDen[jl3 * HEADS + h], e3);
        }
    }
    for (; r < nb; r += 16) {
        const unsigned int rec0 = A_rec[rbase + r];
        const unsigned int u0 = KV[(size_t)(rec0 & 0xFFFFFFu) * DIM + lane];
        const float bb0 = bf_lo((unsigned int)bias16[(rbase + r) * 8 + h]);
        const int jl0 = rec0 >> 24;
        float d0 = sQ[jl0 * DIM + lane] * bf_lo(u0);
        d0 += __shfl_xor(d0, 1, 64);
        d0 += __shfl_xor(d0, 2, 64);
        d0 += __shfl_xor(d0, 4, 64);
        const float e0 = __expf(d0 * inv_sqrt_dk + bb0);
        atomicAdd(&sNum[jl0 * DIM + lane], e0 * bf_hi(u0));
        if ((lane & 7) == 0) atomicAdd(&sDen[jl0 * HEADS + h], e0);
    }
    __syncthreads();
    // out-projection phase: one wave per node
    for (int n = wave; n < NPB; n += 16) {
        const int j = jbase + n;
        if (j >= N_NODES) break;
        const float den = sDen[n * HEADS + h] + 1e-12f;
        const float av = sNum[n * DIM + lane] / den;
        float acc = bO[lane];
        #pragma unroll
        for (int k = 0; k < DIM; ++k)
            acc += __shfl(av, k, 64) * WO[k * DIM + lane];
        out[(size_t)j * DIM + lane] = acc;
    }
}

extern "C" void kernel_launch(void* const* d_in, const int* in_sizes, int n_in,
                              void* d_out, int out_size, void* d_ws, size_t ws_size,
                              hipStream_t stream) {
    const float* x    = (const float*)d_in[0];
    const int*   ei   = (const int*)d_in[1];
    const float* ea   = (const float*)d_in[2];
    const float* WQ   = (const float*)d_in[3];
    const float* bQ   = (const float*)d_in[4];
    const float* WK   = (const float*)d_in[5];
    const float* bK   = (const float*)d_in[6];
    const float* WV   = (const float*)d_in[7];
    const float* bV   = (const float*)d_in[8];
    const float* WO   = (const float*)d_in[9];
    const float* bO   = (const float*)d_in[10];
    const float* We1  = (const float*)d_in[11];
    const float* be1  = (const float*)d_in[12];
    const float* We2  = (const float*)d_in[13];
    const float* be2  = (const float*)d_in[14];
    float* out = (float*)d_out;

    char* ws = (char*)d_ws;
    size_t off_b = 0;
    auto alloc = [&](size_t bytes) {
        void* p = ws + off_b;
        off_b += (bytes + 255) & ~(size_t)255;
        return p;
    };
    float*        Q      = (float*)alloc((size_t)N_NODES * DIM * sizeof(float));
    unsigned int* KV     = (unsigned int*)alloc((size_t)N_NODES * DIM * sizeof(unsigned int));
    unsigned int* A_rec  = (unsigned int*)alloc((size_t)NB * ACAP * sizeof(unsigned int));
    uint4*        A_bias = (uint4*)alloc((size_t)NB * ACAP * sizeof(uint4));
    int*          gcur   = (int*)alloc((size_t)NB * sizeof(int));
    h2*           w1p    = (h2*)alloc(512 * sizeof(h2));
    h2*           w2p    = (h2*)alloc(128 * sizeof(h2));

    (void)hipMemsetAsync(gcur, 0, (size_t)NB * sizeof(int), stream);

    pack_weights<<<1, 1024, 0, stream>>>(We1, We2, w1p, w2p);
    mlp_partition<<<(N_EDGES + PART_E - 1) / PART_E, PART_T, 0, stream>>>(
        ei, ea, w1p, be1, w2p, be2, gcur, A_rec, A_bias);
    qkv_proj<<<(N_NODES + 3) / 4, 256, 0, stream>>>(x, WQ, bQ, WK, bK, WV, bV, Q, KV);
    bucket_attn2<<<NB, 1024, 0, stream>>>(gcur, A_rec, A_bias, Q, KV, WO, bO, out);
}

// Round 11
// 378.125 us; speedup vs baseline: 2.4591x; 2.4591x over previous
//
#include <hip/hip_runtime.h>
#include <math.h>

#define N_NODES 50000
#define N_EDGES 1600000
#define DIM 64
#define HEADS 8
#define EDGE_DIM 32

#define NB 512      // destination buckets
#define NPB 98      // nodes per bucket (98*512 = 50176 >= 50000)
#define ACAP 4096   // per-bucket capacity (mean 3125, sd ~56 -> 17 sigma)
#define PART_T 256
#define EPT 4
#define PART_E (PART_T * EPT)  // 1024 edges per partition block

typedef __fp16 h2 __attribute__((ext_vector_type(2)));

// ---- bf16 helpers (RNE round via bit trick; inputs are finite) ----
__device__ __forceinline__ unsigned int f2bf(float f) {
    union { float f; unsigned int u; } c; c.f = f;
    unsigned int u = c.u;
    return (u + 0x7FFFu + ((u >> 16) & 1u)) >> 16;
}
__device__ __forceinline__ float bf_lo(unsigned int u) { return __uint_as_float(u << 16); }
__device__ __forceinline__ float bf_hi(unsigned int u) { return __uint_as_float(u & 0xFFFF0000u); }

// ---------------- K_prep: pack MLP weights as half2 pairs ----------------
__global__ __launch_bounds__(1024) void pack_weights(
    const float* __restrict__ We1, const float* __restrict__ We2,
    h2* __restrict__ w1p, h2* __restrict__ w2p)
{
    const int t = threadIdx.x;
    if (t < 512) {
        const int c = t >> 4, kk = t & 15;
        w1p[t] = __builtin_amdgcn_cvt_pkrtz(We1[(2 * kk) * EDGE_DIM + c],
                                            We1[(2 * kk + 1) * EDGE_DIM + c]);
    } else if (t < 512 + 128) {
        const int u = t - 512;
        const int h = u >> 4, cc = u & 15;
        w2p[u] = __builtin_amdgcn_cvt_pkrtz(We2[(2 * cc) * HEADS + h],
                                            We2[(2 * cc + 1) * HEADS + h]);
    }
}

// ---------------- K_A: MLP + bucket partition (high-occupancy) ----------------
// Streams ei + edge_attr, computes the edge MLP, writes {jl<<24|i, bias[8]bf16}
// into per-bucket regions via block-reserved sequential chunks (write frontier
// = 512 cursors -> L2-resident, full-line fills, no sector waste).
__global__ __launch_bounds__(256) void mlp_partition(
    const int* __restrict__ ei,
    const float* __restrict__ edge_attr,
    const h2* __restrict__ w1p, const float* __restrict__ be1,
    const h2* __restrict__ w2p, const float* __restrict__ be2,
    int* __restrict__ gcur,
    unsigned int* __restrict__ A_rec, uint4* __restrict__ A_bias)
{
    __shared__ int cnt[NB];
    __shared__ int base[NB];
    const int tid = threadIdx.x;
    for (int t = tid; t < NB; t += PART_T) cnt[t] = 0;
    __syncthreads();
    const int e0 = blockIdx.x * PART_E;
    #pragma unroll
    for (int k = 0; k < EPT; ++k) {
        const int e = e0 + k * PART_T + tid;
        if (e < N_EDGES) atomicAdd(&cnt[ei[N_EDGES + e] / NPB], 1);
    }
    __syncthreads();
    for (int t = tid; t < NB; t += PART_T) {
        base[t] = (cnt[t] > 0) ? atomicAdd(&gcur[t], cnt[t]) : 0;
        cnt[t] = 0;  // reuse as local cursor
    }
    __syncthreads();
    for (int k = 0; k < EPT; ++k) {
        const int e = e0 + k * PART_T + tid;
        if (e >= N_EDGES) break;
        const int i = ei[e];
        const int j = ei[N_EDGES + e];
        const int b = j / NPB;
        const int jl = j - b * NPB;
        float a[EDGE_DIM];
        const float4* ar = (const float4*)(edge_attr + (size_t)e * EDGE_DIM);
        #pragma unroll
        for (int q = 0; q < EDGE_DIM / 4; ++q) {
            float4 v = ar[q];
            a[q * 4 + 0] = v.x; a[q * 4 + 1] = v.y;
            a[q * 4 + 2] = v.z; a[q * 4 + 3] = v.w;
        }
        h2 a2[EDGE_DIM / 2];
        #pragma unroll
        for (int kk = 0; kk < EDGE_DIM / 2; ++kk)
            a2[kk] = __builtin_amdgcn_cvt_pkrtz(a[2 * kk], a[2 * kk + 1]);
        float sil[EDGE_DIM];
        #pragma unroll 8
        for (int c = 0; c < EDGE_DIM; ++c) {
            float s = be1[c];
            #pragma unroll
            for (int kk = 0; kk < EDGE_DIM / 2; ++kk)
                s = __builtin_amdgcn_fdot2(a2[kk], w1p[c * 16 + kk], s, false);
            sil[c] = __fdividef(s, 1.0f + __expf(-s));
        }
        h2 s2[EDGE_DIM / 2];
        #pragma unroll
        for (int cc = 0; cc < EDGE_DIM / 2; ++cc)
            s2[cc] = __builtin_amdgcn_cvt_pkrtz(sil[2 * cc], sil[2 * cc + 1]);
        float b0f = be2[0], b1f = be2[1], b2f = be2[2], b3f = be2[3];
        float b4f = be2[4], b5f = be2[5], b6f = be2[6], b7f = be2[7];
        #pragma unroll
        for (int cc = 0; cc < EDGE_DIM / 2; ++cc) {
            b0f = __builtin_amdgcn_fdot2(s2[cc], w2p[0 * 16 + cc], b0f, false);
            b1f = __builtin_amdgcn_fdot2(s2[cc], w2p[1 * 16 + cc], b1f, false);
            b2f = __builtin_amdgcn_fdot2(s2[cc], w2p[2 * 16 + cc], b2f, false);
            b3f = __builtin_amdgcn_fdot2(s2[cc], w2p[3 * 16 + cc], b3f, false);
            b4f = __builtin_amdgcn_fdot2(s2[cc], w2p[4 * 16 + cc], b4f, false);
            b5f = __builtin_amdgcn_fdot2(s2[cc], w2p[5 * 16 + cc], b5f, false);
            b6f = __builtin_amdgcn_fdot2(s2[cc], w2p[6 * 16 + cc], b6f, false);
            b7f = __builtin_amdgcn_fdot2(s2[cc], w2p[7 * 16 + cc], b7f, false);
        }
        uint4 br;
        br.x = f2bf(b0f) | (f2bf(b1f) << 16);
        br.y = f2bf(b2f) | (f2bf(b3f) << 16);
        br.z = f2bf(b4f) | (f2bf(b5f) << 16);
        br.w = f2bf(b6f) | (f2bf(b7f) << 16);
        const int lp = base[b] + atomicAdd(&cnt[b], 1);
        if (lp < ACAP) {
            A_rec[(size_t)b * ACAP + lp]  = ((unsigned)jl << 24) | (unsigned)i;
            A_bias[(size_t)b * ACAP + lp] = br;
        }
    }
}

// ---------------- K_B: per-bucket CSR finalize ----------------
// Per bucket (512 blocks -> 2/CU): degree histogram + scan -> global offs;
// move records to globally-contiguous CSR positions (scatter window ~62 KB -> L2).
__global__ __launch_bounds__(512) void bucket_csr(
    const int* __restrict__ gcur,
    const unsigned int* __restrict__ A_rec, const uint4* __restrict__ A_bias,
    int* __restrict__ offs, int* __restrict__ src_sorted,
    uint4* __restrict__ bias_sorted)
{
    __shared__ int sc[NB];
    __shared__ int ldeg[NPB];
    __shared__ int loff[NPB + 1];
    __shared__ int gbase_s;
    const int tid = threadIdx.x;
    const int b = blockIdx.x;
    // exclusive prefix over bucket counts -> this bucket's global base
    sc[tid] = min(gcur[tid], ACAP);
    __syncthreads();
    for (int o = 1; o < NB; o <<= 1) {
        int t = (tid >= o) ? sc[tid - o] : 0;
        __syncthreads();
        sc[tid] += t;
        __syncthreads();
    }
    if (tid == 0) gbase_s = (b == 0) ? 0 : sc[b - 1];
    if (tid < NPB) ldeg[tid] = 0;
    __syncthreads();
    const int gbase = gbase_s;
    const int nb = min(gcur[b], ACAP);
    // degree histogram
    for (int r = tid; r < nb; r += 512)
        atomicAdd(&ldeg[A_rec[(size_t)b * ACAP + r] >> 24], 1);
    __syncthreads();
    // scan degrees -> local offsets (128-wide is enough for NPB=98)
    if (tid < 128) sc[tid] = (tid < NPB) ? ldeg[tid] : 0;
    __syncthreads();
    for (int o = 1; o < 128; o <<= 1) {
        int t = 0;
        if (tid < 128 && tid >= o) t = sc[tid - o];
        __syncthreads();
        if (tid < 128) sc[tid] += t;
        __syncthreads();
    }
    if (tid == 0) loff[0] = 0;
    if (tid < NPB) { loff[tid + 1] = sc[tid]; ldeg[tid] = 0; }  // ldeg -> cursor
    __syncthreads();
    // global CSR offsets
    const int jbase = b * NPB;
    if (tid < NPB && jbase + tid < N_NODES) offs[jbase + tid] = gbase + loff[tid];
    if (b == NB - 1 && tid == 0) offs[N_NODES] = gbase + nb;
    // move records into CSR order
    for (int r = tid; r < nb; r += 512) {
        const unsigned int rec = A_rec[(size_t)b * ACAP + r];
        const int jl = rec >> 24;
        const int slot = loff[jl] + atomicAdd(&ldeg[jl], 1);
        const int gp = gbase + slot;
        src_sorted[gp] = (int)(rec & 0xFFFFFFu);
        bias_sorted[gp] = A_bias[(size_t)b * ACAP + r];
    }
}

// ---------------- K1: Q/K/V projections; K,V packed bf16 into one uint row ----------------
__global__ __launch_bounds__(256) void qkv_proj(
    const float* __restrict__ x,
    const float* __restrict__ WQ, const float* __restrict__ bQ,
    const float* __restrict__ WK, const float* __restrict__ bK,
    const float* __restrict__ WV, const float* __restrict__ bV,
    float* __restrict__ Q, unsigned int* __restrict__ KV)
{
    __shared__ float sWQ[DIM * DIM];
    __shared__ float sWK[DIM * DIM];
    __shared__ float sWV[DIM * DIM];
    for (int t = threadIdx.x; t < DIM * DIM; t += blockDim.x) {
        sWQ[t] = WQ[t]; sWK[t] = WK[t]; sWV[t] = WV[t];
    }
    __syncthreads();
    const int lane = threadIdx.x & 63;
    const int wave = threadIdx.x >> 6;
    const int n = blockIdx.x * 4 + wave;
    if (n >= N_NODES) return;
    float xl = x[(size_t)n * DIM + lane];
    float aq = bQ[lane], ak = bK[lane], av = bV[lane];
    #pragma unroll
    for (int k = 0; k < DIM; ++k) {
        float xv = __shfl(xl, k, 64);
        aq += xv * sWQ[k * DIM + lane];
        ak += xv * sWK[k * DIM + lane];
        av += xv * sWV[k * DIM + lane];
    }
    Q[(size_t)n * DIM + lane] = aq;
    KV[(size_t)n * DIM + lane] = f2bf(ak) | (f2bf(av) << 16);  // K lo, V hi
}

// ---------------- K3: per-node attention + fused output projection ----------------
__global__ __launch_bounds__(256) void node_attn_out(
    const int* __restrict__ off,
    const int* __restrict__ src_sorted,
    const unsigned short* __restrict__ bias_u16,
    const float* __restrict__ Q, const unsigned int* __restrict__ KV,
    const float* __restrict__ WO, const float* __restrict__ bO,
    float* __restrict__ out)
{
    __shared__ float sWO[DIM * DIM];
    for (int t = threadIdx.x; t < DIM * DIM; t += 256) sWO[t] = WO[t];
    __syncthreads();
    const int lane = threadIdx.x & 63;
    const int wave = threadIdx.x >> 6;
    const int j = blockIdx.x * 4 + wave;
    if (j >= N_NODES) return;
    const int beg = off[j], end = off[j + 1];
    const int h = lane >> 3;
    const float qv = Q[(size_t)j * DIM + lane];
    const float inv_sqrt_dk = 0.35355339059327373f;
    float num = 0.0f;
    float den = 1e-12f;
    int t = beg;
    for (; t + 3 < end; t += 4) {
        const int i0 = src_sorted[t + 0];
        const int i1 = src_sorted[t + 1];
        const int i2 = src_sorted[t + 2];
        const int i3 = src_sorted[t + 3];
        const unsigned int u0 = KV[(size_t)i0 * DIM + lane];
        const unsigned int u1 = KV[(size_t)i1 * DIM + lane];
        const unsigned int u2 = KV[(size_t)i2 * DIM + lane];
        const unsigned int u3 = KV[(size_t)i3 * DIM + lane];
        const float b0 = bf_lo((unsigned int)bias_u16[(size_t)(t + 0) * HEADS + h]);
        const float b1 = bf_lo((unsigned int)bias_u16[(size_t)(t + 1) * HEADS + h]);
        const float b2 = bf_lo((unsigned int)bias_u16[(size_t)(t + 2) * HEADS + h]);
        const float b3 = bf_lo((unsigned int)bias_u16[(size_t)(t + 3) * HEADS + h]);
        float d0 = qv * bf_lo(u0);
        float d1 = qv * bf_lo(u1);
        float d2 = qv * bf_lo(u2);
        float d3 = qv * bf_lo(u3);
        d0 += __shfl_xor(d0, 1, 64); d1 += __shfl_xor(d1, 1, 64);
        d2 += __shfl_xor(d2, 1, 64); d3 += __shfl_xor(d3, 1, 64);
        d0 += __shfl_xor(d0, 2, 64); d1 += __shfl_xor(d1, 2, 64);
        d2 += __shfl_xor(d2, 2, 64); d3 += __shfl_xor(d3, 2, 64);
        d0 += __shfl_xor(d0, 4, 64); d1 += __shfl_xor(d1, 4, 64);
        d2 += __shfl_xor(d2, 4, 64); d3 += __shfl_xor(d3, 4, 64);
        const float e0 = __expf(d0 * inv_sqrt_dk + b0);
        const float e1 = __expf(d1 * inv_sqrt_dk + b1);
        const float e2 = __expf(d2 * inv_sqrt_dk + b2);
        const float e3 = __expf(d3 * inv_sqrt_dk + b3);
        num += e0 * bf_hi(u0) + e1 * bf_hi(u1) + e2 * bf_hi(u2) + e3 * bf_hi(u3);
        den += e0 + e1 + e2 + e3;
    }
    for (; t < end; ++t) {
        const int i0 = src_sorted[t];
        const unsigned int u0 = KV[(size_t)i0 * DIM + lane];
        const float b0 = bf_lo((unsigned int)bias_u16[(size_t)t * HEADS + h]);
        float d0 = qv * bf_lo(u0);
        d0 += __shfl_xor(d0, 1, 64);
        d0 += __shfl_xor(d0, 2, 64);
        d0 += __shfl_xor(d0, 4, 64);
        const float e0 = __expf(d0 * inv_sqrt_dk + b0);
        num += e0 * bf_hi(u0);
        den += e0;
    }
    const float av = num / den;
    float acc = bO[lane];
    #pragma unroll
    for (int k = 0; k < DIM; ++k) {
        acc += __shfl(av, k, 64) * sWO[k * DIM + lane];
    }
    out[(size_t)j * DIM + lane] = acc;
}

extern "C" void kernel_launch(void* const* d_in, const int* in_sizes, int n_in,
                              void* d_out, int out_size, void* d_ws, size_t ws_size,
                              hipStream_t stream) {
    const float* x    = (const float*)d_in[0];
    const int*   ei   = (const int*)d_in[1];
    const float* ea   = (const float*)d_in[2];
    const float* WQ   = (const float*)d_in[3];
    const float* bQ   = (const float*)d_in[4];
    const float* WK   = (const float*)d_in[5];
    const float* bK   = (const float*)d_in[6];
    const float* WV   = (const float*)d_in[7];
    const float* bV   = (const float*)d_in[8];
    const float* WO   = (const float*)d_in[9];
    const float* bO   = (const float*)d_in[10];
    const float* We1  = (const float*)d_in[11];
    const float* be1  = (const float*)d_in[12];
    const float* We2  = (const float*)d_in[13];
    const float* be2  = (const float*)d_in[14];
    float* out = (float*)d_out;

    char* ws = (char*)d_ws;
    size_t off_b = 0;
    auto alloc = [&](size_t bytes) {
        void* p = ws + off_b;
        off_b += (bytes + 255) & ~(size_t)255;
        return p;
    };
    float*        Q           = (float*)alloc((size_t)N_NODES * DIM * sizeof(float));
    unsigned int* KV          = (unsigned int*)alloc((size_t)N_NODES * DIM * sizeof(unsigned int));
    unsigned int* A_rec       = (unsigned int*)alloc((size_t)NB * ACAP * sizeof(unsigned int));
    uint4*        A_bias      = (uint4*)alloc((size_t)NB * ACAP * sizeof(uint4));
    int*          src_sorted  = (int*)alloc((size_t)N_EDGES * sizeof(int));
    uint4*        bias_sorted = (uint4*)alloc((size_t)N_EDGES * sizeof(uint4));
    int*          offs        = (int*)alloc((size_t)(N_NODES + 1) * sizeof(int));
    int*          gcur        = (int*)alloc((size_t)NB * sizeof(int));
    h2*           w1p         = (h2*)alloc(512 * sizeof(h2));
    h2*           w2p         = (h2*)alloc(128 * sizeof(h2));

    (void)hipMemsetAsync(gcur, 0, (size_t)NB * sizeof(int), stream);

    pack_weights<<<1, 1024, 0, stream>>>(We1, We2, w1p, w2p);
    mlp_partition<<<(N_EDGES + PART_E - 1) / PART_E, PART_T, 0, stream>>>(
        ei, ea, w1p, be1, w2p, be2, gcur, A_rec, A_bias);
    bucket_csr<<<NB, 512, 0, stream>>>(gcur, A_rec, A_bias,
                                       offs, src_sorted, bias_sorted);
    qkv_proj<<<(N_NODES + 3) / 4, 256, 0, stream>>>(x, WQ, bQ, WK, bK, WV, bV, Q, KV);
    node_attn_out<<<(N_NODES + 3) / 4, 256, 0, stream>>>(offs, src_sorted,
                                                         (const unsigned short*)bias_sorted,
                                                         Q, KV, WO, bO, out);
}

// Round 12
// 349.764 us; speedup vs baseline: 2.6585x; 1.0811x over previous
//
#include <hip/hip_runtime.h>
#include <math.h>

#define N_NODES 50000
#define N_EDGES 1600000
#define DIM 64
#define HEADS 8
#define EDGE_DIM 32

#define NB 256      // destination buckets
#define NPB 196     // nodes per bucket (196*256 = 50176 >= 50000)
#define ACAP 8192   // per-bucket capacity (mean 6250, sd ~79 -> 24 sigma)
#define PART_T 512
#define EPT 4
#define PART_E (PART_T * EPT)  // 2048 edges per partition block

typedef __fp16 h2 __attribute__((ext_vector_type(2)));

// ---- bf16 helpers (RNE round via bit trick; inputs are finite) ----
__device__ __forceinline__ unsigned int f2bf(float f) {
    union { float f; unsigned int u; } c; c.f = f;
    unsigned int u = c.u;
    return (u + 0x7FFFu + ((u >> 16) & 1u)) >> 16;
}
__device__ __forceinline__ float bf_lo(unsigned int u) { return __uint_as_float(u << 16); }
__device__ __forceinline__ float bf_hi(unsigned int u) { return __uint_as_float(u & 0xFFFF0000u); }

// ---------------- K_prep: pack MLP weights as half2 pairs ----------------
__global__ __launch_bounds__(1024) void pack_weights(
    const float* __restrict__ We1, const float* __restrict__ We2,
    h2* __restrict__ w1p, h2* __restrict__ w2p)
{
    const int t = threadIdx.x;
    if (t < 512) {
        const int c = t >> 4, kk = t & 15;
        w1p[t] = __builtin_amdgcn_cvt_pkrtz(We1[(2 * kk) * EDGE_DIM + c],
                                            We1[(2 * kk + 1) * EDGE_DIM + c]);
    } else if (t < 512 + 128) {
        const int u = t - 512;
        const int h = u >> 4, cc = u & 15;
        w2p[u] = __builtin_amdgcn_cvt_pkrtz(We2[(2 * cc) * HEADS + h],
                                            We2[(2 * cc + 1) * HEADS + h]);
    }
}

// ---------------- K_A: MLP + bucket partition, LDS-staged scatter ----------------
// Records are bucket-sorted in LDS, then copied out so consecutive threads
// write consecutive addresses (~160 B contiguous per bucket chunk) -> full-line
// HBM/L2 writes instead of random 20 B scatter.
__global__ __launch_bounds__(512) void mlp_partition(
    const int* __restrict__ ei,
    const float* __restrict__ edge_attr,
    const h2* __restrict__ w1p, const float* __restrict__ be1,
    const h2* __restrict__ w2p, const float* __restrict__ be2,
    int* __restrict__ gcur,
    unsigned int* __restrict__ A_rec, uint4* __restrict__ A_bias)
{
    __shared__ int cnt[NB];
    __shared__ int base[NB];
    __shared__ int lbase[NB];
    __shared__ int total_s;
    __shared__ unsigned int srec[PART_E];       // 8 KB
    __shared__ uint4 sbias[PART_E];             // 32 KB
    __shared__ unsigned char sbkt[PART_E];      // 2 KB
    const int tid = threadIdx.x;
    if (tid < NB) cnt[tid] = 0;
    __syncthreads();
    const int e0 = blockIdx.x * PART_E;
    #pragma unroll
    for (int k = 0; k < EPT; ++k) {
        const int e = e0 + k * PART_T + tid;
        if (e < N_EDGES) atomicAdd(&cnt[ei[N_EDGES + e] / NPB], 1);
    }
    __syncthreads();
    // inclusive scan of cnt into lbase
    if (tid < NB) lbase[tid] = cnt[tid];
    __syncthreads();
    for (int o = 1; o < NB; o <<= 1) {
        int t = 0;
        if (tid < NB && tid >= o) t = lbase[tid - o];
        __syncthreads();
        if (tid < NB) lbase[tid] += t;
        __syncthreads();
    }
    if (tid < NB) {
        const int inc = lbase[tid];
        const int c = cnt[tid];
        base[tid] = (c > 0) ? atomicAdd(&gcur[tid], c) : 0;
        lbase[tid] = inc - c;          // exclusive
        if (tid == NB - 1) total_s = inc;
        cnt[tid] = 0;                   // reuse as local cursor
    }
    __syncthreads();
    for (int k = 0; k < EPT; ++k) {
        const int e = e0 + k * PART_T + tid;
        if (e >= N_EDGES) break;
        const int i = ei[e];
        const int j = ei[N_EDGES + e];
        const int b = j / NPB;
        const int jl = j - b * NPB;
        float a[EDGE_DIM];
        const float4* ar = (const float4*)(edge_attr + (size_t)e * EDGE_DIM);
        #pragma unroll
        for (int q = 0; q < EDGE_DIM / 4; ++q) {
            float4 v = ar[q];
            a[q * 4 + 0] = v.x; a[q * 4 + 1] = v.y;
            a[q * 4 + 2] = v.z; a[q * 4 + 3] = v.w;
        }
        h2 a2[EDGE_DIM / 2];
        #pragma unroll
        for (int kk = 0; kk < EDGE_DIM / 2; ++kk)
            a2[kk] = __builtin_amdgcn_cvt_pkrtz(a[2 * kk], a[2 * kk + 1]);
        float sil[EDGE_DIM];
        #pragma unroll 8
        for (int c = 0; c < EDGE_DIM; ++c) {
            float s = be1[c];
            #pragma unroll
            for (int kk = 0; kk < EDGE_DIM / 2; ++kk)
                s = __builtin_amdgcn_fdot2(a2[kk], w1p[c * 16 + kk], s, false);
            sil[c] = __fdividef(s, 1.0f + __expf(-s));
        }
        h2 s2[EDGE_DIM / 2];
        #pragma unroll
        for (int cc = 0; cc < EDGE_DIM / 2; ++cc)
            s2[cc] = __builtin_amdgcn_cvt_pkrtz(sil[2 * cc], sil[2 * cc + 1]);
        float b0f = be2[0], b1f = be2[1], b2f = be2[2], b3f = be2[3];
        float b4f = be2[4], b5f = be2[5], b6f = be2[6], b7f = be2[7];
        #pragma unroll
        for (int cc = 0; cc < EDGE_DIM / 2; ++cc) {
            b0f = __builtin_amdgcn_fdot2(s2[cc], w2p[0 * 16 + cc], b0f, false);
            b1f = __builtin_amdgcn_fdot2(s2[cc], w2p[1 * 16 + cc], b1f, false);
            b2f = __builtin_amdgcn_fdot2(s2[cc], w2p[2 * 16 + cc], b2f, false);
            b3f = __builtin_amdgcn_fdot2(s2[cc], w2p[3 * 16 + cc], b3f, false);
            b4f = __builtin_amdgcn_fdot2(s2[cc], w2p[4 * 16 + cc], b4f, false);
            b5f = __builtin_amdgcn_fdot2(s2[cc], w2p[5 * 16 + cc], b5f, false);
            b6f = __builtin_amdgcn_fdot2(s2[cc], w2p[6 * 16 + cc], b6f, false);
            b7f = __builtin_amdgcn_fdot2(s2[cc], w2p[7 * 16 + cc], b7f, false);
        }
        uint4 br;
        br.x = f2bf(b0f) | (f2bf(b1f) << 16);
        br.y = f2bf(b2f) | (f2bf(b3f) << 16);
        br.z = f2bf(b4f) | (f2bf(b5f) << 16);
        br.w = f2bf(b6f) | (f2bf(b7f) << 16);
        const int s = lbase[b] + atomicAdd(&cnt[b], 1);
        srec[s] = ((unsigned)jl << 24) | (unsigned)i;
        sbias[s] = br;
        sbkt[s] = (unsigned char)b;
    }
    __syncthreads();
    // coalesced copy-out: consecutive s -> consecutive global positions per bucket
    const int total = total_s;
    for (int s = tid; s < total; s += PART_T) {
        const int b = sbkt[s];
        const int gp = base[b] + (s - lbase[b]);
        if (gp < ACAP) {
            A_rec[(size_t)b * ACAP + gp]  = srec[s];
            A_bias[(size_t)b * ACAP + gp] = sbias[s];
        }
    }
}

// ---------------- K_B: per-bucket CSR index build (offs, src, perm only) ----------------
// No record movement: writes the CSR offsets, source-node stream, and a
// permutation index into the A arrays (bias stays in place, gathered later).
__global__ __launch_bounds__(512) void bucket_perm(
    const int* __restrict__ gcur,
    const unsigned int* __restrict__ A_rec,
    int* __restrict__ offs, int* __restrict__ src_sorted, int* __restrict__ perm)
{
    __shared__ int sc[NB];
    __shared__ int ldeg[NPB];
    __shared__ int loff[NPB + 1];
    __shared__ int gbase_s;
    const int tid = threadIdx.x;
    const int b = blockIdx.x;
    if (tid < NB) sc[tid] = min(gcur[tid], ACAP);
    __syncthreads();
    for (int o = 1; o < NB; o <<= 1) {
        int t = 0;
        if (tid < NB && tid >= o) t = sc[tid - o];
        __syncthreads();
        if (tid < NB) sc[tid] += t;
        __syncthreads();
    }
    if (tid == 0) gbase_s = (b == 0) ? 0 : sc[b - 1];
    if (tid < NPB) ldeg[tid] = 0;
    __syncthreads();
    const int gbase = gbase_s;
    const int nb = min(gcur[b], ACAP);
    for (int r = tid; r < nb; r += 512)
        atomicAdd(&ldeg[A_rec[(size_t)b * ACAP + r] >> 24], 1);
    __syncthreads();
    if (tid < 256) sc[tid] = (tid < NPB) ? ldeg[tid] : 0;
    __syncthreads();
    for (int o = 1; o < 256; o <<= 1) {
        int t = 0;
        if (tid < 256 && tid >= o) t = sc[tid - o];
        __syncthreads();
        if (tid < 256) sc[tid] += t;
        __syncthreads();
    }
    if (tid == 0) loff[0] = 0;
    if (tid < NPB) { loff[tid + 1] = sc[tid]; ldeg[tid] = 0; }  // ldeg -> cursor
    __syncthreads();
    const int jbase = b * NPB;
    if (tid < NPB && jbase + tid < N_NODES) offs[jbase + tid] = gbase + loff[tid];
    if (b == NB - 1 && tid == 0) offs[N_NODES] = gbase + nb;
    for (int r = tid; r < nb; r += 512) {
        const unsigned int rec = A_rec[(size_t)b * ACAP + r];
        const int jl = rec >> 24;
        const int slot = loff[jl] + atomicAdd(&ldeg[jl], 1);
        const int gp = gbase + slot;
        src_sorted[gp] = (int)(rec & 0xFFFFFFu);
        perm[gp] = b * ACAP + r;
    }
}

// ---------------- K1: Q/K/V projections; K,V packed bf16 into one uint row ----------------
__global__ __launch_bounds__(256) void qkv_proj(
    const float* __restrict__ x,
    const float* __restrict__ WQ, const float* __restrict__ bQ,
    const float* __restrict__ WK, const float* __restrict__ bK,
    const float* __restrict__ WV, const float* __restrict__ bV,
    float* __restrict__ Q, unsigned int* __restrict__ KV)
{
    __shared__ float sWQ[DIM * DIM];
    __shared__ float sWK[DIM * DIM];
    __shared__ float sWV[DIM * DIM];
    for (int t = threadIdx.x; t < DIM * DIM; t += blockDim.x) {
        sWQ[t] = WQ[t]; sWK[t] = WK[t]; sWV[t] = WV[t];
    }
    __syncthreads();
    const int lane = threadIdx.x & 63;
    const int wave = threadIdx.x >> 6;
    const int n = blockIdx.x * 4 + wave;
    if (n >= N_NODES) return;
    float xl = x[(size_t)n * DIM + lane];
    float aq = bQ[lane], ak = bK[lane], av = bV[lane];
    #pragma unroll
    for (int k = 0; k < DIM; ++k) {
        float xv = __shfl(xl, k, 64);
        aq += xv * sWQ[k * DIM + lane];
        ak += xv * sWK[k * DIM + lane];
        av += xv * sWV[k * DIM + lane];
    }
    Q[(size_t)n * DIM + lane] = aq;
    KV[(size_t)n * DIM + lane] = f2bf(ak) | (f2bf(av) << 16);  // K lo, V hi
}

// ---------------- K3: per-node attention + fused output projection ----------------
// Bias gathered via perm from A_bias (L2-hot window that sweeps with j).
__global__ __launch_bounds__(256) void node_attn_out(
    const int* __restrict__ off,
    const int* __restrict__ src_sorted,
    const int* __restrict__ perm,
    const unsigned short* __restrict__ bias_u16,
    const float* __restrict__ Q, const unsigned int* __restrict__ KV,
    const float* __restrict__ WO, const float* __restrict__ bO,
    float* __restrict__ out)
{
    __shared__ float sWO[DIM * DIM];
    for (int t = threadIdx.x; t < DIM * DIM; t += 256) sWO[t] = WO[t];
    __syncthreads();
    const int lane = threadIdx.x & 63;
    const int wave = threadIdx.x >> 6;
    const int j = blockIdx.x * 4 + wave;
    if (j >= N_NODES) return;
    const int beg = off[j], end = off[j + 1];
    const int h = lane >> 3;
    const float qv = Q[(size_t)j * DIM + lane];
    const float inv_sqrt_dk = 0.35355339059327373f;
    float num = 0.0f;
    float den = 1e-12f;
    int t = beg;
    for (; t + 3 < end; t += 4) {
        const int i0 = src_sorted[t + 0];
        const int i1 = src_sorted[t + 1];
        const int i2 = src_sorted[t + 2];
        const int i3 = src_sorted[t + 3];
        const int p0 = perm[t + 0];
        const int p1 = perm[t + 1];
        const int p2 = perm[t + 2];
        const int p3 = perm[t + 3];
        const unsigned int u0 = KV[(size_t)i0 * DIM + lane];
        const unsigned int u1 = KV[(size_t)i1 * DIM + lane];
        const unsigned int u2 = KV[(size_t)i2 * DIM + lane];
        const unsigned int u3 = KV[(size_t)i3 * DIM + lane];
        const float b0 = bf_lo((unsigned int)bias_u16[(size_t)p0 * HEADS + h]);
        const float b1 = bf_lo((unsigned int)bias_u16[(size_t)p1 * HEADS + h]);
        const float b2 = bf_lo((unsigned int)bias_u16[(size_t)p2 * HEADS + h]);
        const float b3 = bf_lo((unsigned int)bias_u16[(size_t)p3 * HEADS + h]);
        float d0 = qv * bf_lo(u0);
        float d1 = qv * bf_lo(u1);
        float d2 = qv * bf_lo(u2);
        float d3 = qv * bf_lo(u3);
        d0 += __shfl_xor(d0, 1, 64); d1 += __shfl_xor(d1, 1, 64);
        d2 += __shfl_xor(d2, 1, 64); d3 += __shfl_xor(d3, 1, 64);
        d0 += __shfl_xor(d0, 2, 64); d1 += __shfl_xor(d1, 2, 64);
        d2 += __shfl_xor(d2, 2, 64); d3 += __shfl_xor(d3, 2, 64);
        d0 += __shfl_xor(d0, 4, 64); d1 += __shfl_xor(d1, 4, 64);
        d2 += __shfl_xor(d2, 4, 64); d3 += __shfl_xor(d3, 4, 64);
        const float e0 = __expf(d0 * inv_sqrt_dk + b0);
        const float e1 = __expf(d1 * inv_sqrt_dk + b1);
        const float e2 = __expf(d2 * inv_sqrt_dk + b2);
        const float e3 = __expf(d3 * inv_sqrt_dk + b3);
        num += e0 * bf_hi(u0) + e1 * bf_hi(u1) + e2 * bf_hi(u2) + e3 * bf_hi(u3);
        den += e0 + e1 + e2 + e3;
    }
    for (; t < end; ++t) {
        const int i0 = src_sorted[t];
        const unsigned int u0 = KV[(size_t)i0 * DIM + lane];
        const float b0 = bf_lo((unsigned int)bias_u16[(size_t)perm[t] * HEADS + h]);
        float d0 = qv * bf_lo(u0);
        d0 += __shfl_xor(d0, 1, 64);
        d0 += __shfl_xor(d0, 2, 64);
        d0 += __shfl_xor(d0, 4, 64);
        const float e0 = __expf(d0 * inv_sqrt_dk + b0);
        num += e0 * bf_hi(u0);
        den += e0;
    }
    const float av = num / den;
    float acc = bO[lane];
    #pragma unroll
    for (int k = 0; k < DIM; ++k) {
        acc += __shfl(av, k, 64) * sWO[k * DIM + lane];
    }
    out[(size_t)j * DIM + lane] = acc;
}

extern "C" void kernel_launch(void* const* d_in, const int* in_sizes, int n_in,
                              void* d_out, int out_size, void* d_ws, size_t ws_size,
                              hipStream_t stream) {
    const float* x    = (const float*)d_in[0];
    const int*   ei   = (const int*)d_in[1];
    const float* ea   = (const float*)d_in[2];
    const float* WQ   = (const float*)d_in[3];
    const float* bQ   = (const float*)d_in[4];
    const float* WK   = (const float*)d_in[5];
    const float* bK   = (const float*)d_in[6];
    const float* WV   = (const float*)d_in[7];
    const float* bV   = (const float*)d_in[8];
    const float* WO   = (const float*)d_in[9];
    const float* bO   = (const float*)d_in[10];
    const float* We1  = (const float*)d_in[11];
    const float* be1  = (const float*)d_in[12];
    const float* We2  = (const float*)d_in[13];
    const float* be2  = (const float*)d_in[14];
    float* out = (float*)d_out;

    char* ws = (char*)d_ws;
    size_t off_b = 0;
    auto alloc = [&](size_t bytes) {
        void* p = ws + off_b;
        off_b += (bytes + 255) & ~(size_t)255;
        return p;
    };
    float*        Q          = (float*)alloc((size_t)N_NODES * DIM * sizeof(float));
    unsigned int* KV         = (unsigned int*)alloc((size_t)N_NODES * DIM * sizeof(unsigned int));
    unsigned int* A_rec      = (unsigned int*)alloc((size_t)NB * ACAP * sizeof(unsigned int));
    uint4*        A_bias     = (uint4*)alloc((size_t)NB * ACAP * sizeof(uint4));
    int*          src_sorted = (int*)alloc((size_t)N_EDGES * sizeof(int));
    int*          perm       = (int*)alloc((size_t)N_EDGES * sizeof(int));
    int*          offs       = (int*)alloc((size_t)(N_NODES + 1) * sizeof(int));
    int*          gcur       = (int*)alloc((size_t)NB * sizeof(int));
    h2*           w1p        = (h2*)alloc(512 * sizeof(h2));
    h2*           w2p        = (h2*)alloc(128 * sizeof(h2));

    (void)hipMemsetAsync(gcur, 0, (size_t)NB * sizeof(int), stream);

    pack_weights<<<1, 1024, 0, stream>>>(We1, We2, w1p, w2p);
    mlp_partition<<<(N_EDGES + PART_E - 1) / PART_E, PART_T, 0, stream>>>(
        ei, ea, w1p, be1, w2p, be2, gcur, A_rec, A_bias);
    bucket_perm<<<NB, 512, 0, stream>>>(gcur, A_rec, offs, src_sorted, perm);
    qkv_proj<<<(N_NODES + 3) / 4, 256, 0, stream>>>(x, WQ, bQ, WK, bK, WV, bV, Q, KV);
    node_attn_out<<<(N_NODES + 3) / 4, 256, 0, stream>>>(offs, src_sorted, perm,
                                                         (const unsigned short*)A_bias,
                                                         Q, KV, WO, bO, out);
}